// Round 1
// baseline (2744.780 us; speedup 1.0000x reference)
//
#include <hip/hip_runtime.h>
#include <hip/hip_bf16.h>
#include <math.h>

typedef short bf16x8 __attribute__((ext_vector_type(8)));
typedef float f32x4 __attribute__((ext_vector_type(4)));
using bf16 = __hip_bfloat16;

namespace {
constexpr int kL = 6, kD = 768, kH = 12, kFF = 3072, kV = 50257, kS = 1024, kB = 2;
constexpr int kT = kB * kS;
constexpr int kVP = 50304;        // V padded to multiple of 128
constexpr float kScale = 0.125f;  // 1/sqrt(DK=64)
}

__device__ __forceinline__ void async16(const void* g, void* l) {
  __builtin_amdgcn_global_load_lds((const __attribute__((address_space(1))) void*)g,
                                   (__attribute__((address_space(3))) void*)l, 16, 0, 0);
}
__device__ __forceinline__ float gelu_exact(float x) {
  return 0.5f * x * (1.0f + erff(x * 0.70710678118654752f));
}

// ---- weight transpose + f32->bf16 convert: src [z][R][C] f32 -> dst [z][C][R] bf16 ----
__global__ __launch_bounds__(256) void k_transpose_cvt(const float* __restrict__ src,
                                                       bf16* __restrict__ dst, int R, int C) {
  __shared__ float tile[32][33];
  const size_t zoff = (size_t)blockIdx.z * R * C;
  src += zoff; dst += zoff;
  const int c0 = blockIdx.x * 32, r0 = blockIdx.y * 32;
  for (int i = threadIdx.y; i < 32; i += 8)
    tile[i][threadIdx.x] = src[(size_t)(r0 + i) * C + c0 + threadIdx.x];
  __syncthreads();
  for (int i = threadIdx.y; i < 32; i += 8)
    dst[(size_t)(c0 + i) * R + r0 + threadIdx.x] = __float2bfloat16(tile[threadIdx.x][i]);
}

// ---- emb f32 [V][D] -> bf16 [VP][D], zero-padded rows ----
__global__ __launch_bounds__(256) void k_cvt_emb(const float* __restrict__ emb, bf16* __restrict__ out) {
  const int i4 = blockIdx.x * 256 + threadIdx.x;
  if (i4 >= kVP * kD / 4) return;
  const size_t e = (size_t)i4 * 4;
  const int row = (int)(e / kD);
  union { ushort4 u; bf16 h[4]; } t;
  if (row < kV) {
    float4 v = *(const float4*)(emb + e);
    t.h[0] = __float2bfloat16(v.x); t.h[1] = __float2bfloat16(v.y);
    t.h[2] = __float2bfloat16(v.z); t.h[3] = __float2bfloat16(v.w);
  } else {
    t.u = make_ushort4(0, 0, 0, 0);
  }
  *(ushort4*)((ushort*)out + e) = t.u;
}

// ---- x = emb[ids] + pe  (fp32) ----
__global__ __launch_bounds__(256) void k_embed(const int* __restrict__ ids, const float* __restrict__ emb,
                                               const float* __restrict__ pe, float* __restrict__ x) {
  const int i4 = blockIdx.x * 256 + threadIdx.x;
  if (i4 >= kT * kD / 4) return;
  const size_t e = (size_t)i4 * 4;
  const int tok = (int)(e / kD), d = (int)(e % kD);
  const int s = tok & (kS - 1);
  const int id = ids[tok];
  float4 ev = *(const float4*)(emb + (size_t)id * kD + d);
  float4 pv = *(const float4*)(pe + (size_t)s * kD + d);
  float4 o = make_float4(ev.x + pv.x, ev.y + pv.y, ev.z + pv.z, ev.w + pv.w);
  *(float4*)(x + e) = o;
}

// ---- LayerNorm (fp32 in) -> bf16 out. One row per block (D=768, 256 threads x 3) ----
__global__ __launch_bounds__(256) void k_ln(const float* __restrict__ x, const float* __restrict__ w,
                                            const float* __restrict__ bb, bf16* __restrict__ out) {
  const int row = blockIdx.x;
  const float* xr = x + (size_t)row * kD;
  float v[3];
#pragma unroll
  for (int i = 0; i < 3; ++i) v[i] = xr[threadIdx.x + i * 256];
  float s = v[0] + v[1] + v[2];
  float s2 = v[0] * v[0] + v[1] * v[1] + v[2] * v[2];
#pragma unroll
  for (int off = 1; off < 64; off <<= 1) { s += __shfl_xor(s, off); s2 += __shfl_xor(s2, off); }
  __shared__ float red[8];
  const int wave = threadIdx.x >> 6;
  if ((threadIdx.x & 63) == 0) { red[wave] = s; red[4 + wave] = s2; }
  __syncthreads();
  s = red[0] + red[1] + red[2] + red[3];
  s2 = red[4] + red[5] + red[6] + red[7];
  const float mu = s * (1.0f / kD);
  const float var = s2 * (1.0f / kD) - mu * mu;
  const float inv = rsqrtf(var + 1e-5f);
#pragma unroll
  for (int i = 0; i < 3; ++i) {
    const int d = threadIdx.x + i * 256;
    out[(size_t)row * kD + d] = __float2bfloat16((v[i] - mu) * inv * w[d] + bb[d]);
  }
}

// ---- GEMM: C[M,N] = A[M,K](bf16) x Bt[N,K](bf16, = B^T), 128x128 tile, BK=32, 4 waves ----
// EPI: 0 bf16-out | 1 f32 + resid | 2 bf16 bias+gelu | 3 f32 bias+resid | 4 f32 col-guard (LM head)
template <int EPI>
__global__ __launch_bounds__(256) void k_gemm(const bf16* __restrict__ A, const bf16* __restrict__ B0,
                                              long strideBz, const float* bias, const float* resid,
                                              float* outF, bf16* outB0, long strideOz,
                                              int K, int ldc, int nvalid) {
  __shared__ __align__(16) bf16 As[128 * 32];
  __shared__ __align__(16) bf16 Bs[128 * 32];
  const bf16* Bt = B0 + (size_t)blockIdx.z * strideBz;
  bf16* outB = outB0 + (size_t)blockIdx.z * strideOz;
  const int m0 = blockIdx.y * 128, n0 = blockIdx.x * 128;
  const int t = threadIdx.x, lane = t & 63;
  const int wr = (t >> 6) >> 1, wc = (t >> 6) & 1;
  const int arow = t >> 2, koff = (t & 3) * 8;  // staging: 4x16B chunks per 64B row
  f32x4 acc[4][4] = {};
  for (int k0 = 0; k0 < K; k0 += 32) {
    async16(A + (size_t)(m0 + arow) * K + k0 + koff, As + (size_t)t * 8);
    async16(A + (size_t)(m0 + arow + 64) * K + k0 + koff, As + (size_t)(256 + t) * 8);
    async16(Bt + (size_t)(n0 + arow) * K + k0 + koff, Bs + (size_t)t * 8);
    async16(Bt + (size_t)(n0 + arow + 64) * K + k0 + koff, Bs + (size_t)(256 + t) * 8);
    __syncthreads();  // drains vmcnt(0) for global_load_lds
    bf16x8 af[4], bfr[4];
#pragma unroll
    for (int f = 0; f < 4; ++f) {
      af[f] = *(const bf16x8*)(As + (wr * 64 + f * 16 + (lane & 15)) * 32 + (lane >> 4) * 8);
      bfr[f] = *(const bf16x8*)(Bs + (wc * 64 + f * 16 + (lane & 15)) * 32 + (lane >> 4) * 8);
    }
#pragma unroll
    for (int i = 0; i < 4; ++i)
#pragma unroll
      for (int j = 0; j < 4; ++j)
        acc[i][j] = __builtin_amdgcn_mfma_f32_16x16x32_bf16(af[i], bfr[j], acc[i][j], 0, 0, 0);
    __syncthreads();
  }
#pragma unroll
  for (int i = 0; i < 4; ++i) {
    const int rbase = m0 + wr * 64 + i * 16 + ((lane >> 4) << 2);
#pragma unroll
    for (int j = 0; j < 4; ++j) {
      const int col = n0 + wc * 64 + j * 16 + (lane & 15);
      const float bv = (EPI == 2 || EPI == 3) ? bias[col] : 0.0f;
#pragma unroll
      for (int r = 0; r < 4; ++r) {
        const size_t idx = (size_t)(rbase + r) * ldc + col;
        float v = acc[i][j][r] + bv;
        if (EPI == 2) v = gelu_exact(v);
        if (EPI == 1 || EPI == 3) v += resid[idx];
        if (EPI == 0 || EPI == 2) outB[idx] = __float2bfloat16(v);
        else if (EPI != 4 || col < nvalid) outF[idx] = v;
      }
    }
  }
}

// ---- fused causal flash attention: grid (S/128, H, B), 4 waves x 32 q-rows, 64-key tiles ----
__global__ __launch_bounds__(256) void k_attn(const bf16* __restrict__ Q, const bf16* __restrict__ Kg,
                                              const bf16* __restrict__ Vg, const int* __restrict__ amask,
                                              bf16* __restrict__ O) {
  __shared__ __align__(16) bf16 Ks[64][72];       // keys x dk, +8 pad (bank stride 4)
  __shared__ __align__(16) bf16 Vts[64][72];      // dk x keys (transposed), +8 pad
  __shared__ __align__(16) bf16 Ps[4][32][72];    // per-wave P for D-layout -> A-layout
  const int qt = blockIdx.x, h = blockIdx.y, b = blockIdx.z;
  const int t = threadIdx.x, lane = t & 63, wv = t >> 6;
  const size_t base = ((size_t)b * kS) * kD + h * 64;
  const int q0 = qt * 128;
  const int* mrow = amask + b * kS;
  // Q fragments straight from global (rows are wave-private, read once)
  bf16x8 qf[2][2];
#pragma unroll
  for (int fm = 0; fm < 2; ++fm)
#pragma unroll
    for (int kk = 0; kk < 2; ++kk)
      qf[fm][kk] = *(const bf16x8*)(Q + base + (size_t)(q0 + wv * 32 + fm * 16 + (lane & 15)) * kD +
                                    kk * 32 + (lane >> 4) * 8);
  float m_run[2][4], l_run[2][4];
  f32x4 acco[2][4] = {};
#pragma unroll
  for (int fm = 0; fm < 2; ++fm)
#pragma unroll
    for (int r = 0; r < 4; ++r) { m_run[fm][r] = -1e30f; l_run[fm][r] = 0.0f; }
  const int nkt = 2 * qt + 2;  // key tiles of 64, up to q0+127
  for (int kt = 0; kt < nkt; ++kt) {
    const int k0 = kt * 64;
    for (int c = t; c < 512; c += 256) {  // K tile: 64 rows x 128B
      const int row = c >> 3, off = (c & 7) * 8;
      *(int4*)&Ks[row][off] = *(const int4*)(Kg + base + (size_t)(k0 + row) * kD + off);
    }
    for (int c = t; c < 512; c += 256) {  // V tile transposed into Vts[d][kv]
      const int kv = c >> 3, d0 = (c & 7) * 8;
      union { int4 i4v; ushort us[8]; } tv;
      tv.i4v = *(const int4*)(Vg + base + (size_t)(k0 + kv) * kD + d0);
#pragma unroll
      for (int j = 0; j < 8; ++j) *(ushort*)&Vts[d0 + j][kv] = tv.us[j];
    }
    __syncthreads();
    // S = Q K^T  (per wave: 32 rows x 64 keys)
    f32x4 accs[2][4] = {};
#pragma unroll
    for (int fn = 0; fn < 4; ++fn) {
      bf16x8 kf0 = *(const bf16x8*)&Ks[fn * 16 + (lane & 15)][(lane >> 4) * 8];
      bf16x8 kf1 = *(const bf16x8*)&Ks[fn * 16 + (lane & 15)][32 + (lane >> 4) * 8];
#pragma unroll
      for (int fm = 0; fm < 2; ++fm) {
        accs[fm][fn] = __builtin_amdgcn_mfma_f32_16x16x32_bf16(qf[fm][0], kf0, accs[fm][fn], 0, 0, 0);
        accs[fm][fn] = __builtin_amdgcn_mfma_f32_16x16x32_bf16(qf[fm][1], kf1, accs[fm][fn], 0, 0, 0);
      }
    }
    // mask + online softmax (row stats via 16-lane shfl_xor groups)
#pragma unroll
    for (int fm = 0; fm < 2; ++fm)
#pragma unroll
      for (int r = 0; r < 4; ++r) {
        const int qglob = q0 + wv * 32 + fm * 16 + ((lane >> 4) << 2) + r;
        float sv[4];
        float mx = -1e30f;
#pragma unroll
        for (int fn = 0; fn < 4; ++fn) {
          const int kglob = k0 + fn * 16 + (lane & 15);
          const bool keep = (kglob <= qglob) && (mrow[kglob] != 0);
          sv[fn] = keep ? accs[fm][fn][r] * kScale : -1e9f;
          mx = fmaxf(mx, sv[fn]);
        }
#pragma unroll
        for (int off = 1; off < 16; off <<= 1) mx = fmaxf(mx, __shfl_xor(mx, off));
        const float mnew = fmaxf(m_run[fm][r], mx);
        const float alpha = __expf(m_run[fm][r] - mnew);
        m_run[fm][r] = mnew;
        float rs = 0.0f;
#pragma unroll
        for (int fn = 0; fn < 4; ++fn) {
          const float p = __expf(sv[fn] - mnew);
          rs += p;
          Ps[wv][fm * 16 + ((lane >> 4) << 2) + r][fn * 16 + (lane & 15)] = __float2bfloat16(p);
        }
#pragma unroll
        for (int off = 1; off < 16; off <<= 1) rs += __shfl_xor(rs, off);
        l_run[fm][r] = l_run[fm][r] * alpha + rs;
#pragma unroll
        for (int fo = 0; fo < 4; ++fo) acco[fm][fo][r] *= alpha;
      }
    // O += P V   (P re-read from LDS in A-layout; same-wave LDS is in-order)
    bf16x8 pa[2][2];
#pragma unroll
    for (int fm = 0; fm < 2; ++fm)
#pragma unroll
      for (int kk = 0; kk < 2; ++kk)
        pa[fm][kk] = *(const bf16x8*)&Ps[wv][fm * 16 + (lane & 15)][kk * 32 + (lane >> 4) * 8];
#pragma unroll
    for (int fo = 0; fo < 4; ++fo) {
      bf16x8 vb0 = *(const bf16x8*)&Vts[fo * 16 + (lane & 15)][(lane >> 4) * 8];
      bf16x8 vb1 = *(const bf16x8*)&Vts[fo * 16 + (lane & 15)][32 + (lane >> 4) * 8];
#pragma unroll
      for (int fm = 0; fm < 2; ++fm) {
        acco[fm][fo] = __builtin_amdgcn_mfma_f32_16x16x32_bf16(pa[fm][0], vb0, acco[fm][fo], 0, 0, 0);
        acco[fm][fo] = __builtin_amdgcn_mfma_f32_16x16x32_bf16(pa[fm][1], vb1, acco[fm][fo], 0, 0, 0);
      }
    }
    __syncthreads();
  }
#pragma unroll
  for (int fm = 0; fm < 2; ++fm)
#pragma unroll
    for (int r = 0; r < 4; ++r) {
      const int row = q0 + wv * 32 + fm * 16 + ((lane >> 4) << 2) + r;
      const float invl = 1.0f / l_run[fm][r];
#pragma unroll
      for (int fo = 0; fo < 4; ++fo)
        O[base + (size_t)row * kD + fo * 16 + (lane & 15)] = __float2bfloat16(acco[fm][fo][r] * invl);
    }
}

extern "C" void kernel_launch(void* const* d_in, const int* in_sizes, int n_in,
                              void* d_out, int out_size, void* d_ws, size_t ws_size,
                              hipStream_t stream) {
  (void)in_sizes; (void)n_in; (void)out_size; (void)ws_size;
  const int* ids = (const int*)d_in[0];
  const int* amask = (const int*)d_in[1];
  const float* emb = (const float*)d_in[2];
  const float* pe = (const float*)d_in[3];
  const float* wq = (const float*)d_in[4];
  const float* wk = (const float*)d_in[5];
  const float* wv = (const float*)d_in[6];
  const float* wo = (const float*)d_in[7];
  const float* ln1w = (const float*)d_in[8];
  const float* ln1b = (const float*)d_in[9];
  const float* ln2w = (const float*)d_in[10];
  const float* ln2b = (const float*)d_in[11];
  const float* w1 = (const float*)d_in[12];
  const float* b1 = (const float*)d_in[13];
  const float* w2 = (const float*)d_in[14];
  const float* b2 = (const float*)d_in[15];
  const float* lnfw = (const float*)d_in[16];
  const float* lnfb = (const float*)d_in[17];
  float* out = (float*)d_out;

  // workspace layout (~197 MB total)
  char* wsp = (char*)d_ws;
  size_t off = 0;
  auto alloc = [&](size_t bytes) { void* p = wsp + off; off += (bytes + 255) & ~(size_t)255; return p; };
  const size_t DD = (size_t)kD * kD, DF = (size_t)kD * kFF;
  bf16* qkvT = (bf16*)alloc(3 * kL * DD * 2);  // [3][L][D][D]  (wq^T, wk^T, wv^T)
  bf16* woT  = (bf16*)alloc(kL * DD * 2);      // [L][D][D]
  bf16* w1T  = (bf16*)alloc(kL * DF * 2);      // [L][FF][D]
  bf16* w2T  = (bf16*)alloc(kL * DF * 2);      // [L][D][FF]
  bf16* embB = (bf16*)alloc((size_t)kVP * kD * 2);
  float* x   = (float*)alloc((size_t)kT * kD * 4);
  bf16* hb   = (bf16*)alloc((size_t)kT * kD * 2);
  bf16* qkv  = (bf16*)alloc(3 * (size_t)kT * kD * 2);
  bf16* ob   = (bf16*)alloc((size_t)kT * kD * 2);
  bf16* ffb  = (bf16*)alloc((size_t)kT * kFF * 2);

  const dim3 tb(32, 8);
  k_transpose_cvt<<<dim3(kD / 32, kD / 32, kL), tb, 0, stream>>>(wq, qkvT, kD, kD);
  k_transpose_cvt<<<dim3(kD / 32, kD / 32, kL), tb, 0, stream>>>(wk, qkvT + kL * DD, kD, kD);
  k_transpose_cvt<<<dim3(kD / 32, kD / 32, kL), tb, 0, stream>>>(wv, qkvT + 2 * kL * DD, kD, kD);
  k_transpose_cvt<<<dim3(kD / 32, kD / 32, kL), tb, 0, stream>>>(wo, woT, kD, kD);
  k_transpose_cvt<<<dim3(kFF / 32, kD / 32, kL), tb, 0, stream>>>(w1, w1T, kD, kFF);
  k_transpose_cvt<<<dim3(kD / 32, kFF / 32, kL), tb, 0, stream>>>(w2, w2T, kFF, kD);
  k_cvt_emb<<<(kVP * kD / 4) / 256, 256, 0, stream>>>(emb, embB);
  k_embed<<<(kT * kD / 4) / 256, 256, 0, stream>>>(ids, emb, pe, x);

  for (int l = 0; l < kL; ++l) {
    k_ln<<<kT, 256, 0, stream>>>(x, ln1w + l * kD, ln1b + l * kD, hb);
    k_gemm<0><<<dim3(kD / 128, kT / 128, 3), 256, 0, stream>>>(
        hb, qkvT + l * DD, (long)(kL * DD), nullptr, nullptr, nullptr, qkv, (long)((size_t)kT * kD),
        kD, kD, 0);
    k_attn<<<dim3(kS / 128, kH, kB), 256, 0, stream>>>(qkv, qkv + (size_t)kT * kD,
                                                       qkv + 2 * (size_t)kT * kD, amask, ob);
    k_gemm<1><<<dim3(kD / 128, kT / 128, 1), 256, 0, stream>>>(
        ob, woT + l * DD, 0, nullptr, x, x, nullptr, 0, kD, kD, 0);
    k_ln<<<kT, 256, 0, stream>>>(x, ln2w + l * kD, ln2b + l * kD, hb);
    k_gemm<2><<<dim3(kFF / 128, kT / 128, 1), 256, 0, stream>>>(
        hb, w1T + l * DF, 0, b1 + l * kFF, nullptr, nullptr, ffb, 0, kD, kFF, 0);
    k_gemm<3><<<dim3(kD / 128, kT / 128, 1), 256, 0, stream>>>(
        ffb, w2T + l * DF, 0, b2 + l * kD, x, x, nullptr, 0, kFF, kD, 0);
  }
  k_ln<<<kT, 256, 0, stream>>>(x, lnfw, lnfb, hb);
  k_gemm<4><<<dim3(kVP / 128, kT / 128, 1), 256, 0, stream>>>(
      hb, embB, 0, nullptr, nullptr, out, nullptr, 0, kD, kV, kV);
}